// Round 6
// baseline (34879.205 us; speedup 1.0000x reference)
//
#include <hip/hip_runtime.h>
#include <hip/hip_bf16.h>

typedef __hip_bfloat16 bf16;
typedef unsigned short u16;
typedef unsigned int u32;

#define B_ 50
#define L_ 1024
#define H_ 512
#define N_ 512
#define BL_ 51200        // B_*L_
#define HBL_ 26214400    // H_*BL_
#define KSZ_ 524288      // H_*L_
#define PI_F 3.14159265358979323846f
#define MARK_BF16 0x3F803F80u

__device__ __forceinline__ float u2f(u16 u){ union{u32 i; float f;} v; v.i = ((u32)u)<<16; return v.f; }
__device__ __forceinline__ u16  f2u(float x){ bf16 b = __float2bfloat16(x); return *(u16*)&b; }

__device__ __forceinline__ float ld_in(const void* p, int i, bool bff){
  if (bff){ u16 v = ((const u16*)p)[i]; union{u32 a; float f;} u; u.a = ((u32)v)<<16; return u.f; }
  return ((const float*)p)[i];
}

__device__ __forceinline__ float gelu_f(float x){
  float t = tanhf(0.7978845608028654f*(x + 0.044715f*x*x*x));
  return 0.5f*x*(1.0f + t);
}

// ---------------- kernel synthesis ----------------
__global__ __launch_bounds__(256) void kV(float* __restrict__ Vre, float* __restrict__ Vim){
  int idx = blockIdx.x*256 + threadIdx.x;        // < N_*L_
  int n = idx >> 10, l = idx & 1023;
  int ph = (n*l) % 2000;                         // exact phase reduction
  float ang = (float)ph * (PI_F/1000.f);
  float mag = expf(-5e-4f*(float)l);
  float s, c;
  sincosf(ang, &s, &c);
  Vre[idx] = mag*c;
  Vim[idx] = mag*s;
}

__global__ __launch_bounds__(256) void kX(const u32* __restrict__ mk,
                                          const void* __restrict__ Cre, const void* __restrict__ Cim,
                                          float* __restrict__ Xre, float* __restrict__ Xim){
  const bool bff = (*mk == MARK_BF16);
  int idx = blockIdx.x*256 + threadIdx.x;        // < 6*H_*N_
  int n = idx & (N_-1);
  float ar = -0.5f, ai = PI_F*(float)n;
  float ex = expf(-5e-4f);
  float s, c;
  sincosf(1e-3f*ai, &s, &c);
  float dre = ex*c - 1.f;
  float dim = ex*s;
  float inv = 1.f/(ar*ar + ai*ai);
  float dBre = (dre*ar + dim*ai)*inv;
  float dBim = (dim*ar - dre*ai)*inv;
  float cr = ld_in(Cre, idx, bff), ci = ld_in(Cim, idx, bff);
  Xre[idx] = cr*dBre - ci*dBim;
  Xim[idx] = cr*dBim + ci*dBre;
}

__global__ __launch_bounds__(256) void kK(const float* __restrict__ Xre, const float* __restrict__ Xim,
                                          const float* __restrict__ Vre, const float* __restrict__ Vim,
                                          float* __restrict__ Kout){
  int kh0 = blockIdx.x*16;
  int l = blockIdx.y*256 + threadIdx.x;
  float acc[16];
  #pragma unroll
  for (int t=0;t<16;++t) acc[t]=0.f;
  for (int n=0;n<N_;++n){
    float vr = Vre[n*L_ + l], vi = Vim[n*L_ + l];
    #pragma unroll
    for (int t=0;t<16;++t){
      acc[t] += Xre[(kh0+t)*N_ + n]*vr - Xim[(kh0+t)*N_ + n]*vi;
    }
  }
  #pragma unroll
  for (int t=0;t<16;++t) Kout[(kh0+t)*L_ + l] = 2.f*acc[t];
}

// ---------------- embedding ----------------
__global__ __launch_bounds__(256) void kEmbed(const u32* __restrict__ mk,
                                              const void* __restrict__ x, const void* __restrict__ W,
                                              const void* __restrict__ be, u16* __restrict__ out){
  const bool bff = (*mk == MARK_BF16);
  int t = blockIdx.x*256 + threadIdx.x;          // < HBL_/4
  int e = t*4;
  int h = e / BL_;
  int col = e - h*BL_;
  float w = ld_in(W, h, bff), bb = ld_in(be, h, bff);
  ushort4 o;
  o.x = f2u(ld_in(x, col+0, bff)*w + bb);
  o.y = f2u(ld_in(x, col+1, bff)*w + bb);
  o.z = f2u(ld_in(x, col+2, bff)*w + bb);
  o.w = f2u(ld_in(x, col+3, bff)*w + bb);
  *(ushort4*)(out + e) = o;
}

// ---------------- zero Z + loss accumulator ----------------
__global__ __launch_bounds__(256) void kZero(uint4* __restrict__ Z, float* __restrict__ lossAcc){
  int t = blockIdx.x*256 + threadIdx.x;          // < HBL_*2/16
  Z[t] = make_uint4(0u,0u,0u,0u);
  if (t == 0) *lossAcc = 0.f;
}

// ---------------- LayerNorm over h; optional 2nd input added; OUT-OF-PLACE ----------------
__global__ __launch_bounds__(256) void kLN(const u32* __restrict__ mk,
                                           const u16* __restrict__ U, const u16* __restrict__ U2,
                                           const void* __restrict__ g, const void* __restrict__ bb,
                                           int off, u16* __restrict__ Vout){
  const bool bff = (*mk == MARK_BF16);
  int col = blockIdx.x*256 + threadIdx.x;        // < BL_
  float s = 0.f, s2 = 0.f;
  if (U2){
    for (int h=0; h<H_; ++h){ float xv = u2f(U[h*BL_+col]) + u2f(U2[h*BL_+col]); s += xv; s2 += xv*xv; }
  } else {
    for (int h=0; h<H_; ++h){ float xv = u2f(U[h*BL_+col]); s += xv; s2 += xv*xv; }
  }
  float mean = s*(1.f/512.f);
  float var  = s2*(1.f/512.f) - mean*mean;
  float rstd = rsqrtf(var + 1e-5f);
  if (U2){
    for (int h=0; h<H_; ++h){
      float xv = u2f(U[h*BL_+col]) + u2f(U2[h*BL_+col]);
      Vout[h*BL_+col] = f2u((xv - mean)*rstd*ld_in(g, off+h, bff) + ld_in(bb, off+h, bff));
    }
  } else {
    for (int h=0; h<H_; ++h){
      float xv = u2f(U[h*BL_+col]);
      Vout[h*BL_+col] = f2u((xv - mean)*rstd*ld_in(g, off+h, bff) + ld_in(bb, off+h, bff));
    }
  }
}

// ---------------- causal conv per (h,b); OUT-OF-PLACE ----------------
__global__ __launch_bounds__(256) void kConv(const u32* __restrict__ mk,
                                             const u16* __restrict__ V, const float* __restrict__ Kk,
                                             const void* __restrict__ Dv, int dOff,
                                             const u16* __restrict__ U,
                                             u16* __restrict__ Y, int skip, int doGelu){
  const bool bff = (*mk == MARK_BF16);
  int h = blockIdx.x, b = blockIdx.y;
  int tid = threadIdx.x;
  __shared__ float sv[1024];
  __shared__ float sk[1024];
  int rowoff = (h*B_ + b)*L_;
  ushort4 vv4 = *(const ushort4*)(V + rowoff + tid*4);
  sv[tid*4+0] = u2f(vv4.x); sv[tid*4+1] = u2f(vv4.y);
  sv[tid*4+2] = u2f(vv4.z); sv[tid*4+3] = u2f(vv4.w);
  ((float4*)sk)[tid] = ((const float4*)(Kk + h*L_))[tid];
  __syncthreads();
  int l0 = tid*4;
  float a0=0.f,a1=0.f,a2=0.f,a3=0.f;
  for (int j4=0; j4<l0; j4+=4){
    float4 kk = *(const float4*)(sk + j4);
    int base = l0 - j4;
    float4 w0 = *(const float4*)(sv + base - 4);
    float4 w1 = *(const float4*)(sv + base);
    a0 += kk.x*w1.x + kk.y*w0.w + kk.z*w0.z + kk.w*w0.y;
    a1 += kk.x*w1.y + kk.y*w1.x + kk.z*w0.w + kk.w*w0.z;
    a2 += kk.x*w1.z + kk.y*w1.y + kk.z*w1.x + kk.w*w0.w;
    a3 += kk.x*w1.w + kk.y*w1.z + kk.z*w1.y + kk.w*w1.x;
  }
  {
    float k0=sk[l0], k1=sk[l0+1], k2=sk[l0+2], k3=sk[l0+3];
    float v0=sv[0], v1=sv[1], v2=sv[2], v3=sv[3];
    a0 += k0*v0;
    a1 += k0*v1 + k1*v0;
    a2 += k0*v2 + k1*v1 + k2*v0;
    a3 += k0*v3 + k1*v2 + k2*v1 + k3*v0;
  }
  float Dh = ld_in(Dv, dOff + h, bff);
  float y0 = tanhf(a0 + sv[l0+0]*Dh);
  float y1 = tanhf(a1 + sv[l0+1]*Dh);
  float y2 = tanhf(a2 + sv[l0+2]*Dh);
  float y3 = tanhf(a3 + sv[l0+3]*Dh);
  if (skip){
    ushort4 uu = *(const ushort4*)(U + rowoff + l0);
    y0 += u2f(uu.x); y1 += u2f(uu.y); y2 += u2f(uu.z); y3 += u2f(uu.w);
  }
  if (doGelu){
    y0 = gelu_f(y0); y1 = gelu_f(y1); y2 = gelu_f(y2); y3 = gelu_f(y3);
  }
  ushort4 o;
  o.x = f2u(y0); o.y = f2u(y1); o.z = f2u(y2); o.w = f2u(y3);
  *(ushort4*)(Y + rowoff + l0) = o;
}

// ---------------- FF: Z[m,n] = gelu(sum_k W[k,m]*Y[k,n] + bias[m]); loss vs old Z ----------------
__global__ __launch_bounds__(256) void kFF(const u32* __restrict__ mk,
                                           const u16* __restrict__ Yin, const void* __restrict__ W,
                                           const void* __restrict__ bias, u16* Zout,
                                           const u16* Zold, float* __restrict__ lossAcc,
                                           int doLoss){
  const bool bff = (*mk == MARK_BF16);
  __shared__ float As[16][64];
  __shared__ float Bs[16][64];
  int tid = threadIdx.x;
  int tx = tid & 15, ty = tid >> 4;
  int m0 = blockIdx.y*64, n0 = blockIdx.x*64;
  float acc[4][4];
  #pragma unroll
  for (int i=0;i<4;++i){
    #pragma unroll
    for (int j=0;j<4;++j) acc[i][j]=0.f;
  }
  int lcol = tx*4;
  for (int k0=0; k0<H_; k0+=16){
    int wbase = (k0+ty)*H_ + m0 + lcol;
    As[ty][lcol+0] = ld_in(W, wbase+0, bff);
    As[ty][lcol+1] = ld_in(W, wbase+1, bff);
    As[ty][lcol+2] = ld_in(W, wbase+2, bff);
    As[ty][lcol+3] = ld_in(W, wbase+3, bff);
    ushort4 bv4 = *(const ushort4*)(Yin + (k0+ty)*BL_ + n0 + lcol);
    Bs[ty][lcol+0] = u2f(bv4.x);
    Bs[ty][lcol+1] = u2f(bv4.y);
    Bs[ty][lcol+2] = u2f(bv4.z);
    Bs[ty][lcol+3] = u2f(bv4.w);
    __syncthreads();
    #pragma unroll
    for (int kk=0; kk<16; ++kk){
      float4 av = *(const float4*)&As[kk][ty*4];
      float4 bv = *(const float4*)&Bs[kk][tx*4];
      float a[4]  = {av.x, av.y, av.z, av.w};
      float bb4[4]= {bv.x, bv.y, bv.z, bv.w};
      #pragma unroll
      for (int i=0;i<4;++i){
        #pragma unroll
        for (int j=0;j<4;++j) acc[i][j] += a[i]*bb4[j];
      }
    }
    __syncthreads();
  }
  float ls = 0.f;
  #pragma unroll
  for (int i=0;i<4;++i){
    int m = m0 + ty*4 + i;
    float bi = ld_in(bias, m, bff);
    ushort4 o;
    float vals[4];
    #pragma unroll
    for (int j=0;j<4;++j) vals[j] = gelu_f(acc[i][j] + bi);
    if (doLoss){
      const u16* zp = Zold + m*BL_ + n0 + tx*4;
      #pragma unroll
      for (int j=0;j<4;++j){ float d = vals[j] - u2f(zp[j]); ls += d*d; }
    }
    o.x = f2u(vals[0]); o.y = f2u(vals[1]); o.z = f2u(vals[2]); o.w = f2u(vals[3]);
    *(ushort4*)(Zout + m*BL_ + n0 + tx*4) = o;
  }
  if (doLoss){
    __shared__ float red[256];
    red[tid] = ls;
    __syncthreads();
    for (int off=128; off>0; off>>=1){
      if (tid < off) red[tid] += red[tid+off];
      __syncthreads();
    }
    if (tid==0) atomicAdd(lossAcc, red[0]);
  }
}

// ---------------- scalars: loss + n_deq (f32 out) ----------------
__global__ void kScalars(const float* __restrict__ lossAcc, float* __restrict__ outp){
  if (threadIdx.x == 0 && blockIdx.x == 0){
    outp[500] = *lossAcc * (1.f/26214400.f);
    outp[26214901] = 8.0f;
  }
}

// ---------------- transpose [H,B,L] bf16 -> out[b,l,h] f32 ----------------
__global__ __launch_bounds__(256) void kTrans(const u16* __restrict__ Z, float* __restrict__ out){
  __shared__ u16 st[64][68];
  int b = blockIdx.z, h0 = blockIdx.y*64, l0 = blockIdx.x*64;
  int tid = threadIdx.x;
  int r = tid >> 2, q = tid & 3;
  const u16* src = Z + ((h0+r)*B_ + b)*L_ + l0 + q*16;
  #pragma unroll
  for (int c=0; c<4; ++c){
    ushort4 v = *(const ushort4*)(src + c*4);
    st[r][q*16 + c*4 + 0] = v.x;
    st[r][q*16 + c*4 + 1] = v.y;
    st[r][q*16 + c*4 + 2] = v.z;
    st[r][q*16 + c*4 + 3] = v.w;
  }
  __syncthreads();
  int i = tid & 63;
  int j0 = tid >> 6;
  for (int jj = j0; jj < 64; jj += 4){
    out[(size_t)(b*L_ + l0 + jj)*H_ + h0 + i] = u2f(st[i][jj]);
  }
}

// ---------------- mean over l ----------------
__global__ __launch_bounds__(256) void kMeanL(const u16* __restrict__ Z, float* __restrict__ Hb){
  int lane = threadIdx.x & 63;
  int ridx = blockIdx.x*4 + (threadIdx.x >> 6);  // = ho*B_+b, < H_*B_
  const u16* row = Z + (size_t)ridx*L_;
  float s = 0.f;
  for (int ii=lane; ii<L_; ii+=64) s += u2f(row[ii]);
  for (int off=32; off>0; off>>=1) s += __shfl_down(s, off, 64);
  if (lane==0){
    int ho = ridx / B_, b = ridx - ho*B_;
    Hb[b*H_ + ho] = s*(1.f/1024.f);
  }
}

__global__ __launch_bounds__(256) void kLogits(const u32* __restrict__ mk,
                                               const float* __restrict__ Hb, const void* __restrict__ Wfc,
                                               const void* __restrict__ bfc, float* __restrict__ outp){
  const bool bff = (*mk == MARK_BF16);
  int t = blockIdx.x*256 + threadIdx.x;
  if (t < 500){
    int b = t/10, c = t - (t/10)*10;
    float s = ld_in(bfc, c, bff);
    for (int ho=0; ho<H_; ++ho) s += Hb[b*H_+ho]*ld_in(Wfc, ho*10+c, bff);
    outp[t] = s;
  }
}

extern "C" void kernel_launch(void* const* d_in, const int* in_sizes, int n_in,
                              void* d_out, int out_size, void* d_ws, size_t ws_size,
                              hipStream_t stream) {
  (void)in_sizes; (void)n_in; (void)out_size; (void)ws_size;
  const void* x      = d_in[0];
  const void* W_emb  = d_in[1];
  const void* b_emb  = d_in[2];
  const void* C_re   = d_in[3];
  const void* C_im   = d_in[4];
  const void* Dp     = d_in[5];
  const void* ln_g   = d_in[6];
  const void* ln_b   = d_in[7];
  const void* W_feed = d_in[8];
  const void* b_feed = d_in[9];
  const void* W_fc   = d_in[10];
  const void* b_fc   = d_in[11];
  const u32* mk = (const u32*)d_in[5];
  float* outp = (float*)d_out;                   // OUTPUT IS FLOAT32

  // ws (~170 MB): Kbuf f32[6*KSZ] | Zb | T1 | T2 (bf16 HBL each) | Hbar | lossAcc
  float* Kbuf = (float*)d_ws;
  u16* Zb = (u16*)(Kbuf + 6*KSZ_);
  u16* T1 = Zb + HBL_;
  u16* T2 = T1 + HBL_;
  float* Hbar = (float*)(T2 + HBL_);
  float* lossAcc = Hbar + 25600;
  // X0: bf16 scratch inside d_out (bytes 0..52.4MB of the 104.9MB buffer);
  // dead before the final output kernels write d_out.
  u16* X0 = (u16*)d_out;
  // phase-A f32 scratch carved from T1 (dead until explicit blocks)
  float* Vre = (float*)T1;
  float* Vim = Vre + N_*L_;
  float* Xre = Vim + N_*L_;
  float* Xim = Xre + 6*H_*N_;

  // 1) kernels K
  kV<<<2048, 256, 0, stream>>>(Vre, Vim);
  kX<<<6144, 256, 0, stream>>>(mk, C_re, C_im, Xre, Xim);
  kK<<<dim3(192,4), 256, 0, stream>>>(Xre, Xim, Vre, Vim, Kbuf);

  // 2) embedding -> X0
  kEmbed<<<25600, 256, 0, stream>>>(mk, x, W_emb, b_emb, X0);

  // 3) three explicit S4D blocks, out-of-place ping-pong X0 <-> T2
  u16* cur = X0;
  u16* nxt = T2;
  for (int i=0;i<3;++i){
    kLN<<<200,256,0,stream>>>(mk, cur, nullptr, ln_g, ln_b, i*H_, T1);
    kConv<<<dim3(H_,B_),256,0,stream>>>(mk, T1, Kbuf + i*KSZ_, Dp, i*H_, cur, nxt, 1, 0);
    u16* tmp = cur; cur = nxt; nxt = tmp;
  }
  u16* XINJ = cur;                         // T2
  u16* BT   = nxt;                         // X0: DEQ bounce buffer

  // 4) DEQ: z=0; 8 applications of f
  kZero<<<12800, 256, 0, stream>>>((uint4*)Zb, lossAcc);
  for (int it=0; it<8; ++it){
    int last = (it == 7);
    kLN<<<200,256,0,stream>>>(mk, Zb, XINJ, ln_g, ln_b, 3*H_, T1);
    kConv<<<dim3(H_,B_),256,0,stream>>>(mk, T1, Kbuf + 3*KSZ_, Dp, 3*H_, nullptr, BT, 0, 0);
    kLN<<<200,256,0,stream>>>(mk, BT, nullptr, ln_g, ln_b, 4*H_, T1);
    kConv<<<dim3(H_,B_),256,0,stream>>>(mk, T1, Kbuf + 4*KSZ_, Dp, 4*H_, nullptr, BT, 0, 0);
    kLN<<<200,256,0,stream>>>(mk, BT, nullptr, ln_g, ln_b, 5*H_, T1);
    kConv<<<dim3(H_,B_),256,0,stream>>>(mk, T1, Kbuf + 5*KSZ_, Dp, 5*H_, nullptr, BT, 0, 1);
    kFF<<<dim3(800,8),256,0,stream>>>(mk, BT, W_feed, b_feed, Zb, Zb, lossAcc, last);
  }

  // 5) outputs (X0/XINJ dead; d_out safe to finalize as f32)
  kMeanL<<<6400,256,0,stream>>>(Zb, Hbar);
  kScalars<<<1, 64, 0, stream>>>(lossAcc, outp);
  kTrans<<<dim3(16,8,50),256,0,stream>>>(Zb, outp + 501);
  kLogits<<<2,256,0,stream>>>(mk, Hbar, W_fc, b_fc, outp);
}

// Round 7
// 10313.911 us; speedup vs baseline: 3.3818x; 3.3818x over previous
//
#include <hip/hip_runtime.h>
#include <hip/hip_bf16.h>

typedef __hip_bfloat16 bf16;
typedef unsigned short u16;
typedef unsigned int u32;
typedef __attribute__((ext_vector_type(8))) short short8;
typedef __attribute__((ext_vector_type(4))) float f32x4;

#define B_ 50
#define L_ 1024
#define H_ 512
#define N_ 512
#define BL_ 51200        // B_*L_
#define HBL_ 26214400    // H_*BL_
#define KROW_ 1088       // L_ + 64 zero-pad front
#define PI_F 3.14159265358979323846f
#define MARK_BF16 0x3F803F80u

__device__ __forceinline__ float u2f(u16 u){ union{u32 i; float f;} v; v.i = ((u32)u)<<16; return v.f; }
__device__ __forceinline__ u16  f2u(float x){ bf16 b = __float2bfloat16(x); return *(u16*)&b; }

__device__ __forceinline__ float ld_in(const void* p, int i, bool bff){
  if (bff){ u16 v = ((const u16*)p)[i]; union{u32 a; float f;} u; u.a = ((u32)v)<<16; return u.f; }
  return ((const float*)p)[i];
}

__device__ __forceinline__ float gelu_f(float x){
  float t = tanhf(0.7978845608028654f*(x + 0.044715f*x*x*x));
  return 0.5f*x*(1.0f + t);
}

// ---------------- kernel synthesis ----------------
__global__ __launch_bounds__(256) void kV(float* __restrict__ Vre, float* __restrict__ Vim){
  int idx = blockIdx.x*256 + threadIdx.x;        // < N_*L_
  int n = idx >> 10, l = idx & 1023;
  int ph = (n*l) % 2000;                         // exact phase reduction
  float ang = (float)ph * (PI_F/1000.f);
  float mag = expf(-5e-4f*(float)l);
  float s, c;
  sincosf(ang, &s, &c);
  Vre[idx] = mag*c;
  Vim[idx] = mag*s;
}

__global__ __launch_bounds__(256) void kX(const u32* __restrict__ mk,
                                          const void* __restrict__ Cre, const void* __restrict__ Cim,
                                          float* __restrict__ Xre, float* __restrict__ Xim){
  const bool bff = (*mk == MARK_BF16);
  int idx = blockIdx.x*256 + threadIdx.x;        // < 6*H_*N_
  int n = idx & (N_-1);
  float ar = -0.5f, ai = PI_F*(float)n;
  float ex = expf(-5e-4f);
  float s, c;
  sincosf(1e-3f*ai, &s, &c);
  float dre = ex*c - 1.f;
  float dim = ex*s;
  float inv = 1.f/(ar*ar + ai*ai);
  float dBre = (dre*ar + dim*ai)*inv;
  float dBim = (dim*ar - dre*ai)*inv;
  float cr = ld_in(Cre, idx, bff), ci = ld_in(Cim, idx, bff);
  Xre[idx] = cr*dBre - ci*dBim;
  Xim[idx] = cr*dBim + ci*dBre;
}

// K -> bf16, padded: Kbp[row][t] = 0 for t<64, bf16(K[row][t-64]) else. row = kidx*512+h.
__global__ __launch_bounds__(256) void kK(const float* __restrict__ Xre, const float* __restrict__ Xim,
                                          const float* __restrict__ Vre, const float* __restrict__ Vim,
                                          u16* __restrict__ Kbp){
  int kh0 = blockIdx.x*16;
  int l = blockIdx.y*256 + threadIdx.x;
  float acc[16];
  #pragma unroll
  for (int t=0;t<16;++t) acc[t]=0.f;
  for (int n=0;n<N_;++n){
    float vr = Vre[n*L_ + l], vi = Vim[n*L_ + l];
    #pragma unroll
    for (int t=0;t<16;++t){
      acc[t] += Xre[(kh0+t)*N_ + n]*vr - Xim[(kh0+t)*N_ + n]*vi;
    }
  }
  #pragma unroll
  for (int t=0;t<16;++t) Kbp[(kh0+t)*KROW_ + 64 + l] = f2u(2.f*acc[t]);
  if (blockIdx.y == 0 && threadIdx.x < 64){
    #pragma unroll
    for (int t=0;t<16;++t) Kbp[(kh0+t)*KROW_ + threadIdx.x] = 0;
  }
}

// W_feed [k][m] f32 -> Wbt [m][k] bf16
__global__ __launch_bounds__(256) void kWb(const u32* __restrict__ mk,
                                           const void* __restrict__ W, u16* __restrict__ Wbt){
  const bool bff = (*mk == MARK_BF16);
  int idx = blockIdx.x*256 + threadIdx.x;        // < 262144
  int k = idx >> 9, m = idx & 511;
  Wbt[m*512 + k] = f2u(ld_in(W, k*512 + m, bff));
}

// ---------------- embedding ----------------
__global__ __launch_bounds__(256) void kEmbed(const u32* __restrict__ mk,
                                              const void* __restrict__ x, const void* __restrict__ W,
                                              const void* __restrict__ be, u16* __restrict__ out){
  const bool bff = (*mk == MARK_BF16);
  int t = blockIdx.x*256 + threadIdx.x;          // < HBL_/4
  int e = t*4;
  int h = e / BL_;
  int col = e - h*BL_;
  float w = ld_in(W, h, bff), bb = ld_in(be, h, bff);
  ushort4 o;
  o.x = f2u(ld_in(x, col+0, bff)*w + bb);
  o.y = f2u(ld_in(x, col+1, bff)*w + bb);
  o.z = f2u(ld_in(x, col+2, bff)*w + bb);
  o.w = f2u(ld_in(x, col+3, bff)*w + bb);
  *(ushort4*)(out + e) = o;
}

// ---------------- zero Z + loss accumulator ----------------
__global__ __launch_bounds__(256) void kZero(uint4* __restrict__ Z, float* __restrict__ lossAcc){
  int t = blockIdx.x*256 + threadIdx.x;          // < HBL_*2/16
  Z[t] = make_uint4(0u,0u,0u,0u);
  if (t == 0) *lossAcc = 0.f;
}

// ---------------- LayerNorm over h; parallel (col, h-quarter) split ----------------
__global__ __launch_bounds__(256) void kLN2(const u32* __restrict__ mk,
                                            const u16* __restrict__ U, const u16* __restrict__ U2,
                                            const void* __restrict__ g, const void* __restrict__ bb,
                                            int off, u16* __restrict__ Vout){
  const bool bff = (*mk == MARK_BF16);
  int tx = threadIdx.x & 63, ty = threadIdx.x >> 6;   // tx: col-local, ty: h-quarter
  int col = blockIdx.x*64 + tx;
  int h0 = ty*128;
  float s = 0.f, s2 = 0.f;
  for (int hh=0; hh<128; ++hh){
    int idx = (h0+hh)*BL_ + col;
    float xv = u2f(U[idx]);
    if (U2) xv += u2f(U2[idx]);
    s += xv; s2 += xv*xv;
  }
  __shared__ float rs[4][64], rq[4][64], mean_s[64], rstd_s[64];
  rs[ty][tx] = s; rq[ty][tx] = s2;
  __syncthreads();
  if (ty == 0){
    float st = rs[0][tx]+rs[1][tx]+rs[2][tx]+rs[3][tx];
    float qt = rq[0][tx]+rq[1][tx]+rq[2][tx]+rq[3][tx];
    float mean = st*(1.f/512.f);
    float var  = qt*(1.f/512.f) - mean*mean;
    mean_s[tx] = mean;
    rstd_s[tx] = rsqrtf(var + 1e-5f);
  }
  __syncthreads();
  float mean = mean_s[tx], rstd = rstd_s[tx];
  for (int hh=0; hh<128; ++hh){
    int h = h0+hh;
    int idx = h*BL_ + col;
    float xv = u2f(U[idx]);
    if (U2) xv += u2f(U2[idx]);
    Vout[idx] = f2u((xv - mean)*rstd*ld_in(g, off+h, bff) + ld_in(bb, off+h, bff));
  }
}

// ---------------- MFMA causal conv ----------------
// Per block (c_out, h): Y[b, c_out*64+i] = sum_{ci<=c_out} sum_j V[b, ci*64+j] * T'[j][i],
// T'[j][i] = Kb[h][ (c_out-ci)*64 + 64 + i - j ]  (Kb front-padded with 64 zeros => causal).
// Epilogue: tanh(conv + V*D) (+U skip | gelu), bf16 out.
__global__ __launch_bounds__(256) void kConvM(const u32* __restrict__ mk,
                                              const u16* __restrict__ V, const u16* __restrict__ Kb,
                                              const void* __restrict__ Dv, int dOff,
                                              const u16* __restrict__ U,
                                              u16* __restrict__ Y, int skip, int doGelu){
  const bool bff = (*mk == MARK_BF16);
  int c_out = blockIdx.x;                        // 0..15
  int h = blockIdx.y;                            // 0..511
  int tid = threadIdx.x;
  __shared__ __align__(16) u16 va[64*72];        // A tile: V[b][j], padded rows 50..63 = 0
  __shared__ __align__(16) u16 sk[128];          // K window
  int wv = tid >> 6, lane = tid & 63;
  int nl = lane & 15, quad = lane >> 4;
  int n0 = wv*16;
  f32x4 acc[4];
  #pragma unroll
  for (int mt=0;mt<4;++mt) acc[mt] = (f32x4){0.f,0.f,0.f,0.f};

  int r = tid >> 2, c0 = (tid & 3) * 16;
  const u16* Kbh = Kb + h*KROW_;
  for (int ci = 0; ci <= c_out; ++ci){
    uint4 d0 = make_uint4(0,0,0,0), d1 = make_uint4(0,0,0,0);
    if (r < B_){
      const u16* vp = V + ((h*B_ + r)*L_) + ci*64 + c0;
      d0 = *(const uint4*)vp;
      d1 = *(const uint4*)(vp + 8);
    }
    *(uint4*)&va[r*72 + c0]     = d0;
    *(uint4*)&va[r*72 + c0 + 8] = d1;
    if (tid < 16){
      *(uint4*)&sk[tid*8] = *(const uint4*)(Kbh + (c_out - ci)*64 + tid*8);
    }
    __syncthreads();
    short8 bf0, bf1;
    {
      int s0 = 64 + n0 + nl - quad*8;
      #pragma unroll
      for (int j=0;j<8;++j) bf0[j] = (short)sk[s0 - j];
      s0 -= 32;
      #pragma unroll
      for (int j=0;j<8;++j) bf1[j] = (short)sk[s0 - j];
    }
    #pragma unroll
    for (int mt=0;mt<4;++mt){
      const u16* row = &va[(mt*16 + nl)*72];
      short8 a0 = *(const short8*)&row[quad*8];
      short8 a1 = *(const short8*)&row[32 + quad*8];
      acc[mt] = __builtin_amdgcn_mfma_f32_16x16x32_bf16(a0, bf0, acc[mt], 0,0,0);
      acc[mt] = __builtin_amdgcn_mfma_f32_16x16x32_bf16(a1, bf1, acc[mt], 0,0,0);
    }
    __syncthreads();
  }
  float Dh = ld_in(Dv, dOff + h, bff);
  #pragma unroll
  for (int mt=0;mt<4;++mt){
    #pragma unroll
    for (int reg=0;reg<4;++reg){
      int b = mt*16 + quad*4 + reg;
      if (b < B_){
        int gi = (h*B_ + b)*L_ + c_out*64 + n0 + nl;
        float y = tanhf(acc[mt][reg] + u2f(V[gi])*Dh);
        if (skip) y += u2f(U[gi]);
        if (doGelu) y = gelu_f(y);
        Y[gi] = f2u(y);
      }
    }
  }
}

// ---------------- MFMA FF: Z[m,n] = gelu(sum_k W[k,m]*Y[k,n] + bias[m]); loss vs old Z ----------------
__global__ __launch_bounds__(256) void kFFM(const u32* __restrict__ mk,
                                            const u16* __restrict__ Yin, const u16* __restrict__ Wbt,
                                            const void* __restrict__ bias, u16* Zout,
                                            const u16* Zold, float* __restrict__ lossAcc, int doLoss){
  const bool bff = (*mk == MARK_BF16);
  int n0g = blockIdx.x*64, m0g = blockIdx.y*64;
  int tid = threadIdx.x;
  __shared__ __align__(16) u16 wa[64*72];        // A: Wbt rows (m), cols k
  __shared__ __align__(16) u16 yb[64*72];        // B: Y rows (k), cols n
  __shared__ float red[256];
  int wv = tid >> 6, lane = tid & 63;
  int nl = lane & 15, quad = lane >> 4;
  int n0 = wv*16;
  f32x4 acc[4];
  #pragma unroll
  for (int mt=0;mt<4;++mt) acc[mt] = (f32x4){0.f,0.f,0.f,0.f};
  int r = tid >> 2, c0 = (tid & 3) * 16;
  for (int kc=0; kc<8; ++kc){
    int k0g = kc*64;
    const u16* wp = Wbt + (m0g + r)*512 + k0g + c0;
    *(uint4*)&wa[r*72 + c0]     = *(const uint4*)wp;
    *(uint4*)&wa[r*72 + c0 + 8] = *(const uint4*)(wp + 8);
    const u16* yp = Yin + (size_t)(k0g + r)*BL_ + n0g + c0;
    *(uint4*)&yb[r*72 + c0]     = *(const uint4*)yp;
    *(uint4*)&yb[r*72 + c0 + 8] = *(const uint4*)(yp + 8);
    __syncthreads();
    short8 bf0, bf1;
    #pragma unroll
    for (int j=0;j<8;++j) bf0[j] = (short)yb[(quad*8+j)*72 + n0 + nl];
    #pragma unroll
    for (int j=0;j<8;++j) bf1[j] = (short)yb[(32+quad*8+j)*72 + n0 + nl];
    #pragma unroll
    for (int mt=0;mt<4;++mt){
      const u16* row = &wa[(mt*16 + nl)*72];
      short8 a0 = *(const short8*)&row[quad*8];
      short8 a1 = *(const short8*)&row[32 + quad*8];
      acc[mt] = __builtin_amdgcn_mfma_f32_16x16x32_bf16(a0, bf0, acc[mt], 0,0,0);
      acc[mt] = __builtin_amdgcn_mfma_f32_16x16x32_bf16(a1, bf1, acc[mt], 0,0,0);
    }
    __syncthreads();
  }
  float ls = 0.f;
  #pragma unroll
  for (int mt=0;mt<4;++mt){
    #pragma unroll
    for (int reg=0;reg<4;++reg){
      int m = m0g + mt*16 + quad*4 + reg;
      int col = n0g + n0 + nl;
      float val = gelu_f(acc[mt][reg] + ld_in(bias, m, bff));
      size_t zi = (size_t)m*BL_ + col;
      if (doLoss){ float d = val - u2f(Zold[zi]); ls += d*d; }
      Zout[zi] = f2u(val);
    }
  }
  if (doLoss){
    red[tid] = ls;
    __syncthreads();
    for (int off=128; off>0; off>>=1){
      if (tid < off) red[tid] += red[tid+off];
      __syncthreads();
    }
    if (tid==0) atomicAdd(lossAcc, red[0]);
  }
}

// ---------------- scalars: loss + n_deq (f32 out) ----------------
__global__ void kScalars(const float* __restrict__ lossAcc, float* __restrict__ outp){
  if (threadIdx.x == 0 && blockIdx.x == 0){
    outp[500] = *lossAcc * (1.f/26214400.f);
    outp[26214901] = 8.0f;
  }
}

// ---------------- transpose [H,B,L] bf16 -> out[b,l,h] f32 ----------------
__global__ __launch_bounds__(256) void kTrans(const u16* __restrict__ Z, float* __restrict__ out){
  __shared__ u16 st[64][68];
  int b = blockIdx.z, h0 = blockIdx.y*64, l0 = blockIdx.x*64;
  int tid = threadIdx.x;
  int r = tid >> 2, q = tid & 3;
  const u16* src = Z + ((h0+r)*B_ + b)*L_ + l0 + q*16;
  #pragma unroll
  for (int c=0; c<4; ++c){
    ushort4 v = *(const ushort4*)(src + c*4);
    st[r][q*16 + c*4 + 0] = v.x;
    st[r][q*16 + c*4 + 1] = v.y;
    st[r][q*16 + c*4 + 2] = v.z;
    st[r][q*16 + c*4 + 3] = v.w;
  }
  __syncthreads();
  int i = tid & 63;
  int j0 = tid >> 6;
  for (int jj = j0; jj < 64; jj += 4){
    out[(size_t)(b*L_ + l0 + jj)*H_ + h0 + i] = u2f(st[i][jj]);
  }
}

// ---------------- mean over l ----------------
__global__ __launch_bounds__(256) void kMeanL(const u16* __restrict__ Z, float* __restrict__ Hb){
  int lane = threadIdx.x & 63;
  int ridx = blockIdx.x*4 + (threadIdx.x >> 6);  // = ho*B_+b
  const u16* row = Z + (size_t)ridx*L_;
  float s = 0.f;
  for (int ii=lane; ii<L_; ii+=64) s += u2f(row[ii]);
  for (int off=32; off>0; off>>=1) s += __shfl_down(s, off, 64);
  if (lane==0){
    int ho = ridx / B_, b = ridx - ho*B_;
    Hb[b*H_ + ho] = s*(1.f/1024.f);
  }
}

__global__ __launch_bounds__(256) void kLogits(const u32* __restrict__ mk,
                                               const float* __restrict__ Hb, const void* __restrict__ Wfc,
                                               const void* __restrict__ bfc, float* __restrict__ outp){
  const bool bff = (*mk == MARK_BF16);
  int t = blockIdx.x*256 + threadIdx.x;
  if (t < 500){
    int b = t/10, c = t - (t/10)*10;
    float s = ld_in(bfc, c, bff);
    for (int ho=0; ho<H_; ++ho) s += Hb[b*H_+ho]*ld_in(Wfc, ho*10+c, bff);
    outp[t] = s;
  }
}

extern "C" void kernel_launch(void* const* d_in, const int* in_sizes, int n_in,
                              void* d_out, int out_size, void* d_ws, size_t ws_size,
                              hipStream_t stream) {
  (void)in_sizes; (void)n_in; (void)out_size; (void)ws_size;
  const void* x      = d_in[0];
  const void* W_emb  = d_in[1];
  const void* b_emb  = d_in[2];
  const void* C_re   = d_in[3];
  const void* C_im   = d_in[4];
  const void* Dp     = d_in[5];
  const void* ln_g   = d_in[6];
  const void* ln_b   = d_in[7];
  const void* W_feed = d_in[8];
  const void* b_feed = d_in[9];
  const void* W_fc   = d_in[10];
  const void* b_fc   = d_in[11];
  const u32* mk = (const u32*)d_in[5];
  float* outp = (float*)d_out;

  // ws: Kbp bf16[6*512*1088] | Zb | T1 | T2 (bf16 HBL each) | Hbar f32 | lossAcc f32  (~171 MB)
  u16* Kbp = (u16*)d_ws;
  u16* Zb  = Kbp + 6*H_*KROW_;
  u16* T1  = Zb + HBL_;
  u16* T2  = T1 + HBL_;
  float* Hbar = (float*)(T2 + HBL_);
  float* lossAcc = Hbar + 25600;
  // d_out-resident scratch: X0 (bf16 HBL, bytes 0..52.4MB) + Wbt (0.5MB at byte 100,000,000);
  // both dead before the final output writes.
  u16* X0  = (u16*)d_out;
  u16* Wbt = (u16*)((char*)d_out + 100000000);
  // phase-A f32 scratch carved from T1
  float* Vre = (float*)T1;
  float* Vim = Vre + N_*L_;
  float* Xre = Vim + N_*L_;
  float* Xim = Xre + 6*H_*N_;

  // 1) kernels K (bf16 padded) + W transpose
  kV<<<2048, 256, 0, stream>>>(Vre, Vim);
  kX<<<6144, 256, 0, stream>>>(mk, C_re, C_im, Xre, Xim);
  kK<<<dim3(192,4), 256, 0, stream>>>(Xre, Xim, Vre, Vim, Kbp);
  kWb<<<1024, 256, 0, stream>>>(mk, W_feed, Wbt);

  // 2) embedding -> X0
  kEmbed<<<25600, 256, 0, stream>>>(mk, x, W_emb, b_emb, X0);

  // 3) three explicit S4D blocks, out-of-place ping-pong X0 <-> T2
  u16* cur = X0;
  u16* nxt = T2;
  for (int i=0;i<3;++i){
    kLN2<<<800,256,0,stream>>>(mk, cur, nullptr, ln_g, ln_b, i*H_, T1);
    kConvM<<<dim3(16,H_),256,0,stream>>>(mk, T1, Kbp + i*H_*KROW_, Dp, i*H_, cur, nxt, 1, 0);
    u16* tmp = cur; cur = nxt; nxt = tmp;
  }
  u16* XINJ = cur;                         // T2
  u16* BT   = nxt;                         // X0: DEQ bounce buffer

  // 4) DEQ: z=0; 8 applications of f
  kZero<<<12800, 256, 0, stream>>>((uint4*)Zb, lossAcc);
  for (int it=0; it<8; ++it){
    int last = (it == 7);
    kLN2<<<800,256,0,stream>>>(mk, Zb, XINJ, ln_g, ln_b, 3*H_, T1);
    kConvM<<<dim3(16,H_),256,0,stream>>>(mk, T1, Kbp + 3*H_*KROW_, Dp, 3*H_, nullptr, BT, 0, 0);
    kLN2<<<800,256,0,stream>>>(mk, BT, nullptr, ln_g, ln_b, 4*H_, T1);
    kConvM<<<dim3(16,H_),256,0,stream>>>(mk, T1, Kbp + 4*H_*KROW_, Dp, 4*H_, nullptr, BT, 0, 0);
    kLN2<<<800,256,0,stream>>>(mk, BT, nullptr, ln_g, ln_b, 5*H_, T1);
    kConvM<<<dim3(16,H_),256,0,stream>>>(mk, T1, Kbp + 5*H_*KROW_, Dp, 5*H_, nullptr, BT, 0, 1);
    kFFM<<<dim3(800,8),256,0,stream>>>(mk, BT, Wbt, b_feed, Zb, Zb, lossAcc, last);
  }

  // 5) outputs (X0/Wbt/XINJ dead; d_out safe to finalize as f32)
  kMeanL<<<6400,256,0,stream>>>(Zb, Hbar);
  kScalars<<<1, 64, 0, stream>>>(lossAcc, outp);
  kTrans<<<dim3(16,8,50),256,0,stream>>>(Zb, outp + 501);
  kLogits<<<2,256,0,stream>>>(mk, Hbar, W_fc, b_fc, outp);
}